// Round 1
// baseline (3319.534 us; speedup 1.0000x reference)
//
#include <hip/hip_runtime.h>
#include <math.h>

#define NN 50000
#define EE 800000
#define HID 128
#define HSZ (1u<<21)

// ---------------- device helpers ----------------

static __device__ __forceinline__ float sigmoid_ref(float t) {
  // matches jax.nn.sigmoid monotonicity & s(0)=0.5 dead-band semantics
  if (t >= 0.f) { float e = expf(-t); return 1.f / (1.f + e); }
  float e = expf(t); return e / (1.f + e);
}

// union-find find with path-halving; parent values only decrease -> race-safe
static __device__ __forceinline__ int cc_find(int* par, int v) {
  int r = v;
  int p = par[r];
  while (p != r) {
    int gp = par[p];
    if (gp != p) atomicMin(&par[r], gp);
    r = p; p = gp;
  }
  return r;
}

// ---------------- kernels ----------------

__global__ void k_split_edges(const int* __restrict__ ei, int* __restrict__ s, int* __restrict__ d) {
  int e = blockIdx.x*256 + threadIdx.x;
  if (e < EE) { s[e] = ei[2*e]; d[e] = ei[2*e+1]; }
}

__global__ void k_degree(const int* __restrict__ src, const int* __restrict__ dst, int* __restrict__ deg) {
  int e = blockIdx.x*256 + threadIdx.x;
  if (e < EE && src[e] >= 0) atomicAdd(&deg[dst[e]], 1);
}

__global__ void k_dinv(const int* __restrict__ deg, float* __restrict__ dinv) {
  int i = blockIdx.x*256 + threadIdx.x;
  if (i < NN) dinv[i] = (float)(1.0 / sqrt((double)(deg[i] + 2)));
}

__global__ void k_scan1(const int* __restrict__ deg, int* __restrict__ rp, int* __restrict__ bsum) {
  __shared__ int sh[256];
  int tid = threadIdx.x; int i = blockIdx.x*256 + tid;
  int v = (i < NN) ? deg[i] : 0;
  sh[tid] = v; __syncthreads();
  for (int off = 1; off < 256; off <<= 1) {
    int t = (tid >= off) ? sh[tid-off] : 0;
    __syncthreads(); sh[tid] += t; __syncthreads();
  }
  if (i < NN) rp[i] = sh[tid] - v;            // exclusive within block
  if (tid == 255) bsum[blockIdx.x] = sh[255];
}

__global__ void k_scan2(int* __restrict__ bsum, int* __restrict__ rp, int nb) {
  __shared__ int sh[256];
  int tid = threadIdx.x;
  int v = (tid < nb) ? bsum[tid] : 0;
  sh[tid] = v; __syncthreads();
  for (int off = 1; off < 256; off <<= 1) {
    int t = (tid >= off) ? sh[tid-off] : 0;
    __syncthreads(); sh[tid] += t; __syncthreads();
  }
  if (tid < nb) bsum[tid] = sh[tid] - v;      // exclusive block offsets
  if (tid == 255) rp[NN] = sh[255];           // total
}

__global__ void k_scan3(int* __restrict__ rp, const int* __restrict__ bsum, int* __restrict__ cursor) {
  int i = blockIdx.x*256 + threadIdx.x;
  if (i < NN) { int r = rp[i] + bsum[blockIdx.x]; rp[i] = r; cursor[i] = r; }
}

__global__ void k_csrfill(const int* __restrict__ src, const int* __restrict__ dst,
                          int* __restrict__ cursor, int* __restrict__ csr) {
  int e = blockIdx.x*256 + threadIdx.x;
  if (e < EE) {
    int s = src[e];
    if (s >= 0) { int p = atomicAdd(&cursor[dst[e]], 1); csr[p] = s; }
  }
}

// C[N,128] = concat(A0, A1(gathered)) @ W ; K in {128,256}; tile 64x128, thread 8x4
__global__ __launch_bounds__(256) void k_matmul(
    const float* __restrict__ A0, const int* __restrict__ idx0,
    const float* __restrict__ A1, const int* __restrict__ idx1,
    int K, const float* __restrict__ W, float* __restrict__ C)
{
  __shared__ __align__(16) float As[64][68];   // transposed A chunk, padded
  __shared__ __align__(16) float Bs[64][HID];
  const int tid  = threadIdx.x;
  const int row0 = blockIdx.x * 64;
  const int colg = (tid & 31) * 4;
  const int rowg = (tid >> 5) * 8;
  float acc[8][4];
  #pragma unroll
  for (int i = 0; i < 8; ++i) { acc[i][0]=0.f; acc[i][1]=0.f; acc[i][2]=0.f; acc[i][3]=0.f; }

  for (int kc = 0; kc < K; kc += 64) {
    const float* Asrc = (kc < 128) ? A0 : A1;
    const int*   aidx = (kc < 128) ? idx0 : idx1;
    const int klocal  = (kc < 128) ? kc : (kc - 128);
    #pragma unroll
    for (int t = tid; t < 64*16; t += 256) {     // A: 64 rows x 16 float4
      int r  = t >> 4;
      int k4 = (t & 15) << 2;
      int grow = row0 + r;
      if (grow >= NN) grow = NN - 1;
      int gr = aidx ? aidx[grow] : grow;
      float4 v = *(const float4*)(Asrc + (size_t)gr*HID + klocal + k4);
      As[k4+0][r] = v.x; As[k4+1][r] = v.y; As[k4+2][r] = v.z; As[k4+3][r] = v.w;
    }
    #pragma unroll
    for (int t = tid; t < 64*32; t += 256) {     // B: 64 k x 32 float4
      int kk = t >> 5;
      int c4 = (t & 31) << 2;
      *(float4*)&Bs[kk][c4] = *(const float4*)(W + (size_t)(kc+kk)*HID + c4);
    }
    __syncthreads();
    #pragma unroll 8
    for (int k = 0; k < 64; ++k) {
      float4 a0 = *(const float4*)&As[k][rowg];
      float4 a1 = *(const float4*)&As[k][rowg+4];
      float4 b  = *(const float4*)&Bs[k][colg];
      float ar[8] = {a0.x,a0.y,a0.z,a0.w,a1.x,a1.y,a1.z,a1.w};
      #pragma unroll
      for (int i = 0; i < 8; ++i) {
        acc[i][0] += ar[i]*b.x; acc[i][1] += ar[i]*b.y;
        acc[i][2] += ar[i]*b.z; acc[i][3] += ar[i]*b.w;
      }
    }
    __syncthreads();
  }
  #pragma unroll
  for (int i = 0; i < 8; ++i) {
    int r = row0 + rowg + i;
    if (r < NN) {
      *(float4*)(C + (size_t)r*HID + colg) = make_float4(acc[i][0],acc[i][1],acc[i][2],acc[i][3]);
    }
  }
}

// out[v] = relu?( sum_{e in in(v)} xw[src]*dinv[src]*dinv[v] + 2*dinv[v]^2*xw[v] + b )
__global__ __launch_bounds__(128) void k_conv(
    const float* __restrict__ xw, const int* __restrict__ rp, const int* __restrict__ csr,
    const float* __restrict__ dinv, const float* __restrict__ bias,
    float* __restrict__ out, int relu)
{
  const int v = blockIdx.x;
  const int f = threadIdx.x;
  const int p0 = rp[v], p1 = rp[v+1];
  float acc = 0.f;
  for (int p = p0; p < p1; ++p) {
    int s = csr[p];
    acc += xw[(size_t)s*HID + f] * dinv[s];
  }
  float dv = dinv[v];
  float val = acc * dv + 2.f*dv*dv * xw[(size_t)v*HID + f] + bias[f];
  if (relu) val = fmaxf(val, 0.f);
  out[(size_t)v*HID + f] = val;
}

__global__ __launch_bounds__(256) void k_node_ab(
    const float* __restrict__ h, const float* __restrict__ Wp,
    float* __restrict__ an, float* __restrict__ bn)
{
  int v = blockIdx.x*4 + (threadIdx.x >> 6);
  int l = threadIdx.x & 63;
  if (v >= NN) return;
  float h0 = h[(size_t)v*HID + l];
  float h1 = h[(size_t)v*HID + 64 + l];
  float a = h0*Wp[l]     + h1*Wp[64+l];
  float b = h0*Wp[128+l] + h1*Wp[192+l];
  #pragma unroll
  for (int off = 32; off; off >>= 1) { a += __shfl_down(a, off); b += __shfl_down(b, off); }
  if (l == 0) { an[v] = a; bn[v] = b; }
}

__global__ void k_edge_score(const int* __restrict__ src, const int* __restrict__ dst,
                             const float* __restrict__ an, const float* __restrict__ bn,
                             const float* __restrict__ bp, float* __restrict__ tbuf) {
  int e = blockIdx.x*256 + threadIdx.x;
  if (e >= EE) return;
  int s = src[e], d = dst[e];
  float o = -1.f;
  if (s >= 0 && s != d) o = sigmoid_ref(an[s] + bn[d] + bp[0]);
  tbuf[e] = o;
}

__global__ void k_ccinit(int* __restrict__ par) {
  int i = blockIdx.x*256 + threadIdx.x;
  if (i < NN) par[i] = i;
}

__global__ void k_ccunion(const int* __restrict__ src, const int* __restrict__ dst,
                          const float* __restrict__ tbuf, int* __restrict__ par) {
  int e = blockIdx.x*256 + threadIdx.x;
  if (e >= EE) return;
  if (!(tbuf[e] > 0.5f)) return;
  int ru = cc_find(par, src[e]);
  int rv = cc_find(par, dst[e]);
  while (ru != rv) {
    if (ru < rv) { int t = ru; ru = rv; rv = t; }   // ru > rv: link ru under rv
    int old = atomicCAS(&par[ru], ru, rv);
    if (old == ru) break;
    ru = cc_find(par, old);
    rv = cc_find(par, rv);
  }
}

__global__ void k_cccompress(int* __restrict__ par) {
  int i = blockIdx.x*256 + threadIdx.x;
  if (i < NN) par[i] = cc_find(par, i);
}

// per-thread contiguous chunks with run-length flush (giant-cluster safe)
__global__ void k_wsum(const int* __restrict__ src, const float* __restrict__ tbuf,
                       const int* __restrict__ cl, float* __restrict__ ssum, float* __restrict__ scnt) {
  int t = blockIdx.x*256 + threadIdx.x;
  int base = t * 128;
  int cur = -1; float ss = 0.f, sc = 0.f;
  for (int j = 0; j < 128; ++j) {
    int e = base + j;
    if (e >= EE) break;
    float s = tbuf[e];
    if (s > 0.5f) {
      int c = cl[src[e]];
      if (c == cur) { ss += s; sc += 1.f; }
      else {
        if (cur >= 0) { atomicAdd(&ssum[cur], ss); atomicAdd(&scnt[cur], sc); }
        cur = c; ss = s; sc = 1.f;
      }
    }
  }
  if (cur >= 0) { atomicAdd(&ssum[cur], ss); atomicAdd(&scnt[cur], sc); }
}

__global__ void k_w(float* __restrict__ ssum, const float* __restrict__ scnt) {
  int i = blockIdx.x*256 + threadIdx.x;
  if (i < NN) { float c = scnt[i]; ssum[i] = (c > 0.f) ? ssum[i]/c : 1.f; }
}

// p[cluster[v]] += h[v], run-length flushed per feature lane
__global__ __launch_bounds__(128) void k_poolsum(const float* __restrict__ h,
                                                 const int* __restrict__ cl, float* __restrict__ p) {
  int f = threadIdx.x;
  int base = blockIdx.x * 256;
  int cur = -1; float acc = 0.f;
  for (int j = 0; j < 256; ++j) {
    int v = base + j;
    if (v >= NN) break;
    int c = cl[v];
    float x = h[(size_t)v*HID + f];
    if (c == cur) acc += x;
    else {
      if (cur >= 0) atomicAdd(&p[(size_t)cur*HID + f], acc);
      cur = c; acc = x;
    }
  }
  if (cur >= 0) atomicAdd(&p[(size_t)cur*HID + f], acc);
}

__global__ void k_poolscale(float* __restrict__ p, const float* __restrict__ w) {
  int i = blockIdx.x*256 + threadIdx.x;
  if (i < NN*HID) p[i] *= w[i >> 7];
}

__global__ void k_contract(const int* __restrict__ src, const int* __restrict__ dst,
                           const int* __restrict__ cl, unsigned long long* __restrict__ tab,
                           int* __restrict__ nsrc, int* __restrict__ ndst) {
  int e = blockIdx.x*256 + threadIdx.x;
  if (e >= EE) return;
  int s = src[e], d = dst[e];
  int os = -1, od = 0;
  if (s >= 0 && s != d) {
    int a = cl[s], b = cl[d];
    if (a != b) {
      unsigned long long key = (unsigned long long)a * NN + (unsigned long long)b;
      unsigned long long hh = key * 0x9E3779B97F4A7C15ull;
      unsigned idx = (unsigned)(hh >> 40) & (HSZ - 1);
      while (true) {
        unsigned long long prev = atomicCAS(&tab[idx], ~0ull, key);
        if (prev == ~0ull) { os = a; od = b; break; }  // first inserter keeps the edge
        if (prev == key) break;                        // duplicate -> dead
        idx = (idx + 1) & (HSZ - 1);
      }
    }
  }
  nsrc[e] = os; ndst[e] = od;
}

__global__ __launch_bounds__(256) void k_matvec384(
    const float* __restrict__ h1, const float* __restrict__ xin,
    const float* __restrict__ u1, const int* __restrict__ cl0,
    const float* __restrict__ Wu2, float* __restrict__ zw)
{
  int v = blockIdx.x*4 + (threadIdx.x >> 6);
  int l = threadIdx.x & 63;
  if (v >= NN) return;
  int g = cl0[v];
  float s = h1[(size_t)v*HID + l]        * Wu2[l]
          + h1[(size_t)v*HID + 64 + l]   * Wu2[64+l]
          + xin[(size_t)v*HID + l]       * Wu2[128+l]
          + xin[(size_t)v*HID + 64 + l]  * Wu2[192+l]
          + u1[(size_t)g*HID + l]        * Wu2[256+l]
          + u1[(size_t)g*HID + 64 + l]   * Wu2[320+l];
  #pragma unroll
  for (int off = 32; off; off >>= 1) s += __shfl_down(s, off);
  if (l == 0) zw[v] = s;
}

__global__ void k_final(const float* __restrict__ zw, const int* __restrict__ rp,
                        const int* __restrict__ csr, const float* __restrict__ dinv,
                        const float* __restrict__ bu, float* __restrict__ out) {
  int v = blockIdx.x*256 + threadIdx.x;
  if (v >= NN) return;
  float acc = 0.f;
  int p0 = rp[v], p1 = rp[v+1];
  for (int p = p0; p < p1; ++p) { int s = csr[p]; acc += zw[s]*dinv[s]; }
  float dv = dinv[v];
  float t = acc*dv + 2.f*dv*dv*zw[v] + bu[0];
  out[v] = sigmoid_ref(t);
}

// ---------------- host orchestration ----------------

extern "C" void kernel_launch(void* const* d_in, const int* in_sizes, int n_in,
                              void* d_out, int out_size, void* d_ws, size_t ws_size,
                              hipStream_t stream) {
  const float* x_in = (const float*)d_in[0];
  const int*   ei   = (const int*)d_in[1];
  const float* Wd0 = (const float*)d_in[3];  const float* bd0 = (const float*)d_in[4];
  const float* Wd1 = (const float*)d_in[5];  const float* bd1 = (const float*)d_in[6];
  const float* Wd2 = (const float*)d_in[7];  const float* bd2 = (const float*)d_in[8];
  const float* Wd3 = (const float*)d_in[9];  const float* bd3 = (const float*)d_in[10];
  const float* Wp0 = (const float*)d_in[11]; const float* bp0 = (const float*)d_in[12];
  const float* Wp1 = (const float*)d_in[13]; const float* bp1 = (const float*)d_in[14];
  const float* Wp2 = (const float*)d_in[15]; const float* bp2 = (const float*)d_in[16];
  const float* Wu0 = (const float*)d_in[17]; const float* bu0 = (const float*)d_in[18];
  const float* Wu1 = (const float*)d_in[19]; const float* bu1 = (const float*)d_in[20];
  const float* Wu2 = (const float*)d_in[21]; const float* bu2 = (const float*)d_in[22];
  float* out = (float*)d_out;
  (void)in_sizes; (void)n_in; (void)out_size;

  char* wp = (char*)d_ws;
  auto alloc = [&](size_t bytes) -> void* {
    void* p = (void*)wp;
    wp += (bytes + 255) & ~(size_t)255;
    return p;
  };
  float* B[6]; for (int i = 0; i < 6; ++i) B[i] = (float*)alloc((size_t)NN*HID*4);
  int *srcL[4], *dstL[4];
  for (int i = 0; i < 4; ++i) { srcL[i] = (int*)alloc((size_t)EE*4); dstL[i] = (int*)alloc((size_t)EE*4); }
  float* tbuf = (float*)alloc((size_t)EE*4);
  int* cl[3];   for (int i = 0; i < 3; ++i) cl[i]    = (int*)alloc((size_t)NN*4);
  float* dinvL[4]; for (int i = 0; i < 4; ++i) dinvL[i] = (float*)alloc((size_t)NN*4);
  int* rpL[4]; int* csrL[4];
  for (int i = 0; i < 4; ++i) { rpL[i] = (int*)alloc((size_t)(NN+1)*4); csrL[i] = (int*)alloc((size_t)EE*4); }
  int* deg    = (int*)alloc((size_t)NN*4);
  int* cursor = (int*)alloc((size_t)NN*4);
  int* bsum   = (int*)alloc(256*4);
  float* an   = (float*)alloc((size_t)NN*4);
  float* bn   = (float*)alloc((size_t)NN*4);
  float* ssum = (float*)alloc((size_t)NN*4);
  float* scnt = (float*)alloc((size_t)NN*4);
  float* zw   = (float*)alloc((size_t)NN*4);
  unsigned long long* tab = (unsigned long long*)alloc((size_t)HSZ*8);
  if ((size_t)(wp - (char*)d_ws) > ws_size) return;  // workspace too small: fail loudly

  const int GE = (EE + 255)/256;   // 3125
  const int GN = (NN + 255)/256;   // 196

  k_split_edges<<<GE,256,0,stream>>>(ei, srcL[0], dstL[0]);

  auto build_level = [&](int lev) {
    hipMemsetAsync(deg, 0, (size_t)NN*4, stream);
    k_degree<<<GE,256,0,stream>>>(srcL[lev], dstL[lev], deg);
    k_dinv<<<GN,256,0,stream>>>(deg, dinvL[lev]);
    k_scan1<<<GN,256,0,stream>>>(deg, rpL[lev], bsum);
    k_scan2<<<1,256,0,stream>>>(bsum, rpL[lev], GN);
    k_scan3<<<GN,256,0,stream>>>(rpL[lev], bsum, cursor);
    k_csrfill<<<GE,256,0,stream>>>(srcL[lev], dstL[lev], cursor, csrL[lev]);
  };

  auto do_conv = [&](const float* A0, const int* i0, const float* A1, const int* i1, int K,
                     const float* W, const float* bias, int lev, float* xw, float* outp, int relu) {
    k_matmul<<<(NN+63)/64,256,0,stream>>>(A0, i0, A1, i1, K, W, xw);
    k_conv<<<NN,128,0,stream>>>(xw, rpL[lev], csrL[lev], dinvL[lev], bias, outp, relu);
  };

  auto do_pool = [&](const float* h, int lev, int ci, float* p, const float* Wp, const float* bp) {
    k_node_ab<<<(NN+3)/4,256,0,stream>>>(h, Wp, an, bn);
    k_edge_score<<<GE,256,0,stream>>>(srcL[lev], dstL[lev], an, bn, bp, tbuf);
    k_ccinit<<<GN,256,0,stream>>>(cl[ci]);
    k_ccunion<<<GE,256,0,stream>>>(srcL[lev], dstL[lev], tbuf, cl[ci]);
    k_cccompress<<<GN,256,0,stream>>>(cl[ci]);
    hipMemsetAsync(ssum, 0, (size_t)NN*4, stream);
    hipMemsetAsync(scnt, 0, (size_t)NN*4, stream);
    k_wsum<<<25,256,0,stream>>>(srcL[lev], tbuf, cl[ci], ssum, scnt);
    k_w<<<GN,256,0,stream>>>(ssum, scnt);
    hipMemsetAsync(p, 0, (size_t)NN*HID*4, stream);
    k_poolsum<<<GN,128,0,stream>>>(h, cl[ci], p);
    k_poolscale<<<(NN*HID)/256,256,0,stream>>>(p, ssum);
    hipMemsetAsync(tab, 0xFF, (size_t)HSZ*8, stream);
    k_contract<<<GE,256,0,stream>>>(srcL[lev], dstL[lev], cl[ci], tab, srcL[lev+1], dstL[lev+1]);
  };

  // ---- down path ----
  build_level(0);
  do_conv(x_in, nullptr, nullptr, nullptr, 128, Wd0, bd0, 0, B[5], B[0], 1);  // h1 = B0
  do_pool(B[0], 0, 0, B[3], Wp0, bp0);                                        // p1 = B3, cl0, e1
  build_level(1);
  do_conv(B[3], nullptr, nullptr, nullptr, 128, Wd1, bd1, 1, B[5], B[1], 1);  // h2 = B1
  do_pool(B[1], 1, 1, B[3], Wp1, bp1);                                        // p2 = B3, cl1, e2
  build_level(2);
  do_conv(B[3], nullptr, nullptr, nullptr, 128, Wd2, bd2, 2, B[5], B[2], 1);  // h3 = B2
  do_pool(B[2], 2, 2, B[3], Wp2, bp2);                                        // p3 = B3, cl2, e3
  build_level(3);
  do_conv(B[3], nullptr, nullptr, nullptr, 128, Wd3, bd3, 3, B[5], B[4], 0);  // h4 = B4 (no relu)
  // ---- up path (concats folded into the matmul as [X1|X2]@W, X2 row-gathered) ----
  do_conv(B[2], nullptr, B[4], cl[2], 256, Wu0, bu0, 2, B[5], B[3], 1);       // u0 = B3
  do_conv(B[1], nullptr, B[3], cl[1], 256, Wu1, bu1, 1, B[5], B[4], 1);       // u1 = B4
  k_matvec384<<<(NN+3)/4,256,0,stream>>>(B[0], x_in, B[4], cl[0], Wu2, zw);
  k_final<<<GN,256,0,stream>>>(zw, rpL[0], csrL[0], dinvL[0], bu2, out);
}